// Round 20
// baseline (370.213 us; speedup 1.0000x reference)
//
#include <hip/hip_runtime.h>
#include <hip/hip_bf16.h>
#include <stdint.h>

#define B_   32
#define S_   577
#define SP   640
#define D_   1024
#define H_   16
#define DH   64
#define BH_  (B_*H_)
#define M_   (B_*S_)      // 18464
#define MP2  18688        // padded to 256
#define SCALE_ 0.125f
#define LOG2E_ 1.44269504088896f

typedef __bf16 bf16;
typedef __bf16 bf16x8 __attribute__((ext_vector_type(8)));
typedef __bf16 bf16x4 __attribute__((ext_vector_type(4)));
typedef float  f32x4  __attribute__((ext_vector_type(4)));

__device__ __forceinline__ void gload16(const bf16* g, bf16* l) {
    __builtin_amdgcn_global_load_lds((__attribute__((address_space(1))) void*)g,
                                     (__attribute__((address_space(3))) void*)l, 16, 0, 0);
}

// ---------------- merged cast (hidden + 4 weights) + vT pad-zero, one launch ----------------
__global__ void cast_all(const float* __restrict__ hs, const float* __restrict__ qw,
                         const float* __restrict__ kw, const float* __restrict__ vw,
                         const float* __restrict__ ow,
                         bf16* __restrict__ hsA, bf16* __restrict__ wq, bf16* __restrict__ wk,
                         bf16* __restrict__ wv, bf16* __restrict__ wo, bf16* __restrict__ vT) {
    const int N4H = M_ * 256;                      // hidden float4 count
    const int N4W = 4 * 262144;
    int i = blockIdx.x * blockDim.x + threadIdx.x;
    if (i < N4H + N4W) {
        const float* in; bf16* out; int r;
        if (i < N4H) { in = hs; out = hsA; r = i; }
        else {
            int j = i - N4H, seg = j >> 18; r = j & 262143;
            in  = (seg == 0) ? qw : (seg == 1) ? kw : (seg == 2) ? vw : ow;
            out = (seg == 0) ? wq : (seg == 1) ? wk : (seg == 2) ? wv : wo;
        }
        float4 v = ((const float4*)in)[r];
        bf16x4 o;
        o[0] = (bf16)v.x; o[1] = (bf16)v.y; o[2] = (bf16)v.z; o[3] = (bf16)v.w;
        ((bf16x4*)out)[r] = o;
    } else {
        int j = i - (N4H + N4W);                   // vT pad rows: one thread per (bh*64) row
        if (j < BH_ * 64) {
            bf16* row = vT + (size_t)j * SP + S_;
            #pragma unroll
            for (int k = 0; k < SP - S_; ++k) row[k] = (bf16)0.0f;
        }
    }
}

// ---------------- 256x256 tile, BK=64, double-buffered 2-phase GEMM core (R8, best) ----------------
__device__ __forceinline__ void stage256(const bf16* __restrict__ A, const bf16* __restrict__ B,
                                         int m0, int n0, int K, int kt, bf16* SMbuf) {
    const int tid = threadIdx.x;
    const int wave = tid >> 6;
    #pragma unroll
    for (int ld = 0; ld < 8; ++ld) {
        int li  = ld * 512 + tid;
        int row = (li >> 3) & 255;
        int ch  = (li & 7) ^ (row & 7);
        const bf16* g = ((ld < 4) ? (A + (size_t)(m0 + row) * K)
                                  : (B + (size_t)(n0 + row) * K)) + kt * 64 + ch * 8;
        bf16* l = SMbuf + (size_t)(ld * 512 + wave * 64) * 8;
        gload16(g, l);
    }
}

__device__ __forceinline__ void compute256(const bf16* SMbuf, f32x4 acc[8][4],
                                           int wm, int wn, int r16, int c4) {
    #pragma unroll
    for (int kk = 0; kk < 2; ++kk) {
        bf16x8 bq[4];
        #pragma unroll
        for (int j = 0; j < 4; ++j) {
            int row = wn * 64 + j * 16 + r16;
            int c   = (kk * 4 + c4) ^ (row & 7);
            bq[j] = *(const bf16x8*)(SMbuf + 16384 + row * 64 + c * 8);
        }
        #pragma unroll
        for (int i = 0; i < 8; ++i) {
            int row = wm * 128 + i * 16 + r16;
            int c   = (kk * 4 + c4) ^ (row & 7);
            bf16x8 a = *(const bf16x8*)(SMbuf + row * 64 + c * 8);
            #pragma unroll
            for (int j = 0; j < 4; ++j)
                acc[i][j] = __builtin_amdgcn_mfma_f32_16x16x32_bf16(a, bq[j], acc[i][j], 0, 0, 0);
        }
    }
}

// ---------------- QKV projection: [MP2,1024] x [3072,1024]^T (R8 verbatim) ----------------
__global__ __launch_bounds__(512, 2) void gemm_qkv(const bf16* __restrict__ A, const bf16* __restrict__ Bw,
                                                   const float* __restrict__ qb, const float* __restrict__ kb,
                                                   const float* __restrict__ vb,
                                                   bf16* __restrict__ qk, bf16* __restrict__ vT) {
    __shared__ __align__(16) bf16 SM[2 * 32768];   // 128 KB
    const int bx = blockIdx.x;
    const int bm = bx / 12, bn = bx % 12;
    const int m0 = bm * 256, n0 = bn * 256;
    const int tid = threadIdx.x;
    const int lane = tid & 63, wave = tid >> 6;
    const int wm = wave >> 2, wn = wave & 3;
    const int r16 = lane & 15, c4 = lane >> 4;

    f32x4 acc[8][4];
    #pragma unroll
    for (int i = 0; i < 8; ++i)
        #pragma unroll
        for (int j = 0; j < 4; ++j)
            #pragma unroll
            for (int r = 0; r < 4; ++r) acc[i][j][r] = 0.0f;

    stage256(A, Bw, m0, n0, 1024, 0, SM);
    __syncthreads();
    for (int kt = 0; kt < 16; ++kt) {
        if (kt < 15) stage256(A, Bw, m0, n0, 1024, kt + 1, SM + ((kt + 1) & 1) * 32768);
        compute256(SM + (kt & 1) * 32768, acc, wm, wn, r16, c4);
        __syncthreads();
    }

    if (bn < 8) {
        const float* barr = (bn < 4) ? qb : kb;
        const float mul = (bn < 4) ? SCALE_ * LOG2E_ : 1.0f;
        #pragma unroll
        for (int j = 0; j < 4; ++j) {
            int n = n0 + wn * 64 + j * 16 + r16;
            float bias = barr[n & 1023];
            #pragma unroll
            for (int i = 0; i < 8; ++i) {
                #pragma unroll
                for (int r = 0; r < 4; ++r) {
                    int m = m0 + wm * 128 + i * 16 + c4 * 4 + r;
                    if (m < M_) qk[(size_t)m * 2048 + n] = (bf16)((acc[i][j][r] + bias) * mul);
                }
            }
        }
    } else {
        const int bnp = bn - 8;
        bf16* Ts = SM;                              // [128][259]
        #pragma unroll
        for (int mh = 0; mh < 2; ++mh) {
            if (wm == mh) {
                #pragma unroll
                for (int j = 0; j < 4; ++j) {
                    int nl = wn * 64 + j * 16 + r16;
                    float bias = vb[bnp * 256 + nl];
                    #pragma unroll
                    for (int i = 0; i < 8; ++i) {
                        #pragma unroll
                        for (int r = 0; r < 4; ++r) {
                            int tr = i * 16 + c4 * 4 + r;
                            Ts[tr * 259 + nl] = (bf16)(acc[i][j][r] + bias);
                        }
                    }
                }
            }
            __syncthreads();
            {
                int ml = tid & 127, nh = tid >> 7;
                int gm = m0 + mh * 128 + ml;
                if (gm < M_) {
                    unsigned bb = (unsigned)gm / 577u, s = (unsigned)gm - bb * 577u;
                    bf16* dst = vT + ((size_t)((bb * 16 + bnp * 4 + nh) * 64)) * SP + s;
                    const bf16* src = Ts + ml * 259 + nh * 64;
                    #pragma unroll 8
                    for (int j = 0; j < 64; ++j) dst[(size_t)j * SP] = src[j];
                }
            }
            __syncthreads();
        }
    }
}

// ---------------- output projection: 128x256 tile (R14) ----------------
__device__ __forceinline__ void stage_out(const bf16* __restrict__ A, const bf16* __restrict__ B,
                                          int m0, int n0, int kt, bf16* SMbuf) {
    const int tid = threadIdx.x;
    const int wave = tid >> 6;
    #pragma unroll
    for (int ld = 0; ld < 2; ++ld) {
        int li  = ld * 512 + tid;
        int row = li >> 3;
        int ch  = (li & 7) ^ (row & 7);
        gload16(A + (size_t)(m0 + row) * 1024 + kt * 64 + ch * 8,
                SMbuf + (size_t)(ld * 512 + wave * 64) * 8);
    }
    #pragma unroll
    for (int ld = 0; ld < 4; ++ld) {
        int li  = ld * 512 + tid;
        int row = li >> 3;
        int ch  = (li & 7) ^ (row & 7);
        gload16(B + (size_t)(n0 + row) * 1024 + kt * 64 + ch * 8,
                SMbuf + 8192 + (size_t)(ld * 512 + wave * 64) * 8);
    }
}

__global__ __launch_bounds__(512, 2) void gemm_out(const bf16* __restrict__ A, const bf16* __restrict__ Bw,
                                                   const float* __restrict__ ob, float* __restrict__ out) {
    __shared__ __align__(16) bf16 SM[2 * 24576];   // 96 KB
    const int bx = blockIdx.x;
    const int bm = bx >> 2, bn = bx & 3;
    const int m0 = bm * 128, n0 = bn * 256;
    const int tid = threadIdx.x;
    const int lane = tid & 63, wave = tid >> 6;
    const int wm = wave >> 2, wn = wave & 3;       // wave tile: 64 x 64
    const int r16 = lane & 15, c4 = lane >> 4;

    f32x4 acc[4][4];
    #pragma unroll
    for (int i = 0; i < 4; ++i)
        #pragma unroll
        for (int j = 0; j < 4; ++j)
            #pragma unroll
            for (int r = 0; r < 4; ++r) acc[i][j][r] = 0.0f;

    stage_out(A, Bw, m0, n0, 0, SM);
    __syncthreads();
    for (int kt = 0; kt < 16; ++kt) {
        if (kt < 15) stage_out(A, Bw, m0, n0, kt + 1, SM + ((kt + 1) & 1) * 24576);
        const bf16* SMbuf = SM + (kt & 1) * 24576;
        #pragma unroll
        for (int kk = 0; kk < 2; ++kk) {
            bf16x8 bq[4];
            #pragma unroll
            for (int j = 0; j < 4; ++j) {
                int row = wn * 64 + j * 16 + r16;
                int c   = (kk * 4 + c4) ^ (row & 7);
                bq[j] = *(const bf16x8*)(SMbuf + 8192 + row * 64 + c * 8);
            }
            #pragma unroll
            for (int i = 0; i < 4; ++i) {
                int row = wm * 64 + i * 16 + r16;
                int c   = (kk * 4 + c4) ^ (row & 7);
                bf16x8 a = *(const bf16x8*)(SMbuf + row * 64 + c * 8);
                #pragma unroll
                for (int j = 0; j < 4; ++j)
                    acc[i][j] = __builtin_amdgcn_mfma_f32_16x16x32_bf16(a, bq[j], acc[i][j], 0, 0, 0);
            }
        }
        __syncthreads();
    }

    #pragma unroll
    for (int j = 0; j < 4; ++j) {
        int n = n0 + wn * 64 + j * 16 + r16;
        float bias = ob[n];
        #pragma unroll
        for (int i = 0; i < 4; ++i) {
            #pragma unroll
            for (int r = 0; r < 4; ++r) {
                int m = m0 + wm * 64 + i * 16 + c4 * 4 + r;
                if (m < M_) out[(size_t)m * 1024 + n] = acc[i][j][r] + bias;
            }
        }
    }
}

// ---------------- flash attention v8 (R14/R16/R18 best): QBLK=128, per-qf softmax->PV, 40 KB LDS ----------------
__global__ __launch_bounds__(256) void attn_kernel(const bf16* __restrict__ qk,
                                                   const bf16* __restrict__ vT, bf16* __restrict__ obuf) {
    __shared__ __align__(16) bf16 KV[2][2][4096];      // [buf][K|V][64x64] = 32 KB
    __shared__ __align__(16) char Pls[4 * 2048];       // 8 KB (one P tile per wave)
    const int orig = blockIdx.x;
    const int xcd = orig & 7;
    const int t   = orig >> 3;
    const int qt  = t % 5, bhg = t / 5;
    const int bh  = bhg * 8 + xcd;
    const int b   = bh >> 4, h = bh & 15;
    const int tid = threadIdx.x;
    const int lane = tid & 63, wave = tid >> 6;
    const int r16 = lane & 15, c4 = lane >> 4;
    const int q0  = qt * 128 + wave * 32;
    const int swz = (r16 & 7) << 4;

    const bf16* qp = qk + (size_t)(b * 577) * 2048 + h * 64;
    const bf16* kp = qp + 1024;
    const bf16* vp = vT + (size_t)bh * 64 * SP;

    bf16x8 aq[2][2];
    #pragma unroll
    for (int qf = 0; qf < 2; ++qf)
        #pragma unroll
        for (int c = 0; c < 2; ++c)
            aq[qf][c] = *(const bf16x8*)(qp + (size_t)(q0 + qf * 16 + r16) * 2048 + c * 32 + c4 * 8);

    float mi[2] = {-3.0e38f, -3.0e38f};
    float li[2] = {0.0f, 0.0f};
    f32x4 accO[2][4];
    #pragma unroll
    for (int qf = 0; qf < 2; ++qf)
        #pragma unroll
        for (int nt = 0; nt < 4; ++nt)
            #pragma unroll
            for (int r = 0; r < 4; ++r) accO[qf][nt][r] = 0.0f;

    char* pbase = Pls + wave * 2048 + r16 * 128;

    auto stageKV = [&](int kt, int buf) {
        #pragma unroll
        for (int half = 0; half < 2; ++half) {
            int li  = half * 256 + tid;
            int row = li >> 3;
            int ch  = (li & 7) ^ (row & 7);            // inverse-swizzled source
            bf16* lk = &KV[buf][0][(size_t)(half * 256 + wave * 64) * 8];
            bf16* lv = &KV[buf][1][(size_t)(half * 256 + wave * 64) * 8];
            gload16(kp + (size_t)(kt * 64 + row) * 2048 + ch * 8, lk);
            gload16(vp + (size_t)row * SP + kt * 64 + ch * 8, lv);
        }
    };

    stageKV(0, 0);
    __syncthreads();

    for (int kt = 0; kt < 10; ++kt) {
        const int buf = kt & 1;
        if (kt < 9) stageKV(kt + 1, buf ^ 1);          // async, drained by loop-end barrier

        // ---- K fragments from LDS (swizzled read) + QK^T, both qf ----
        bf16x8 kf[4][2];
        #pragma unroll
        for (int nt = 0; nt < 4; ++nt)
            #pragma unroll
            for (int c = 0; c < 2; ++c) {
                int row = nt * 16 + r16;
                int cc  = (c * 4 + c4) ^ (row & 7);
                kf[nt][c] = *(const bf16x8*)(&KV[buf][0][row * 64 + cc * 8]);
            }
        f32x4 sc[2][4];
        #pragma unroll
        for (int qf = 0; qf < 2; ++qf)
            #pragma unroll
            for (int nt = 0; nt < 4; ++nt) {
                f32x4 z = {0.0f, 0.0f, 0.0f, 0.0f};
                z = __builtin_amdgcn_mfma_f32_16x16x32_bf16(kf[nt][0], aq[qf][0], z, 0, 0, 0);
                sc[qf][nt] = __builtin_amdgcn_mfma_f32_16x16x32_bf16(kf[nt][1], aq[qf][1], z, 0, 0, 0);
            }

        // ---- V fragments once per tile (shared by both qf) ----
        bf16x8 vf[4][2];
        #pragma unroll
        for (int ntd = 0; ntd < 4; ++ntd)
            #pragma unroll
            for (int kk = 0; kk < 2; ++kk) {
                int row = ntd * 16 + r16;
                int cc  = (kk * 4 + c4) ^ (row & 7);
                vf[ntd][kk] = *(const bf16x8*)(&KV[buf][1][row * 64 + cc * 8]);
            }

        // ---- per qf: softmax -> P-LDS -> PV (single P buffer reused) ----
        #pragma unroll
        for (int qf = 0; qf < 2; ++qf) {
            if (kt == 9) {   // only k=576 valid in last tile
                #pragma unroll
                for (int nt = 0; nt < 4; ++nt)
                    #pragma unroll
                    for (int r = 0; r < 4; ++r)
                        if (576 + nt * 16 + c4 * 4 + r >= S_) sc[qf][nt][r] = -3.0e38f;
            }
            float pmax = sc[qf][0][0];
            #pragma unroll
            for (int nt = 0; nt < 4; ++nt)
                #pragma unroll
                for (int r = 0; r < 4; ++r) pmax = fmaxf(pmax, sc[qf][nt][r]);
            pmax = fmaxf(pmax, __shfl_xor(pmax, 16));
            pmax = fmaxf(pmax, __shfl_xor(pmax, 32));

            const bool vrow = (q0 + qf * 16 + r16) < S_;
            int ok = (!vrow) || (pmax <= mi[qf] + 8.0f);
            if (!__all(ok)) {
                float mnew = fmaxf(mi[qf], pmax);
                float fsc  = __builtin_amdgcn_exp2f(mi[qf] - mnew);
                mi[qf] = mnew;
                li[qf] *= fsc;
                float fs0 = __shfl(fsc, c4 * 4 + 0);
                float fs1 = __shfl(fsc, c4 * 4 + 1);
                float fs2 = __shfl(fsc, c4 * 4 + 2);
                float fs3 = __shfl(fsc, c4 * 4 + 3);
                #pragma unroll
                for (int nt = 0; nt < 4; ++nt) {
                    accO[qf][nt][0] *= fs0; accO[qf][nt][1] *= fs1;
                    accO[qf][nt][2] *= fs2; accO[qf][nt][3] *= fs3;
                }
            }
            float p[4][4];
            float rs = 0.0f;
            #pragma unroll
            for (int nt = 0; nt < 4; ++nt)
                #pragma unroll
                for (int r = 0; r < 4; ++r) {
                    p[nt][r] = __builtin_amdgcn_exp2f(sc[qf][nt][r] - mi[qf]);
                    rs += p[nt][r];
                }
            rs += __shfl_xor(rs, 16);
            rs += __shfl_xor(rs, 32);
            li[qf] += rs;
            #pragma unroll
            for (int nt = 0; nt < 4; ++nt) {
                bf16x4 pk;
                pk[0] = (bf16)p[nt][0]; pk[1] = (bf16)p[nt][1];
                pk[2] = (bf16)p[nt][2]; pk[3] = (bf16)p[nt][3];
                *(bf16x4*)(pbase + ((nt * 32 + c4 * 8) ^ swz)) = pk;
            }

            bf16x8 pf[2];
            #pragma unroll
            for (int kk = 0; kk < 2; ++kk)
                pf[kk] = *(const bf16x8*)(pbase + ((kk * 64 + c4 * 16) ^ swz));
            #pragma unroll
            for (int ntd = 0; ntd < 4; ++ntd)
                #pragma unroll
                for (int kk = 0; kk < 2; ++kk)
                    accO[qf][ntd] = __builtin_amdgcn_mfma_f32_16x16x32_bf16(pf[kk], vf[ntd][kk], accO[qf][ntd], 0, 0, 0);
        }

        __syncthreads();   // drains stage(kt+1) + guards buf reuse
    }

    // ---- epilogue ----
    #pragma unroll
    for (int qf = 0; qf < 2; ++qf) {
        float inv = 1.0f / li[qf];
        float rl0 = __shfl(inv, c4 * 4 + 0);
        float rl1 = __shfl(inv, c4 * 4 + 1);
        float rl2 = __shfl(inv, c4 * 4 + 2);
        float rl3 = __shfl(inv, c4 * 4 + 3);
        #pragma unroll
        for (int ntd = 0; ntd < 4; ++ntd) {
            #pragma unroll
            for (int r = 0; r < 4; ++r) {
                int s = q0 + qf * 16 + c4 * 4 + r;
                if (s < S_) {
                    float rl = (r == 0) ? rl0 : (r == 1) ? rl1 : (r == 2) ? rl2 : rl3;
                    obuf[((size_t)(b * S_ + s)) * 1024 + h * 64 + ntd * 16 + r16] =
                        (bf16)(accO[qf][ntd][r] * rl);
                }
            }
        }
    }
}

extern "C" void kernel_launch(void* const* d_in, const int* in_sizes, int n_in,
                              void* d_out, int out_size, void* d_ws, size_t ws_size,
                              hipStream_t stream) {
    const float* hs = (const float*)d_in[0];
    const float* qw = (const float*)d_in[1];
    const float* qb = (const float*)d_in[2];
    const float* kw = (const float*)d_in[3];
    const float* kb = (const float*)d_in[4];
    const float* vw = (const float*)d_in[5];
    const float* vb = (const float*)d_in[6];
    const float* ow = (const float*)d_in[7];
    const float* ob = (const float*)d_in[8];

    char* ws = (char*)d_ws;
    size_t off = 0;
    auto alloc = [&](size_t bytes) { void* p = ws + off; off += (bytes + 255) & ~255UL; return p; };
    bf16* hsA  = (bf16*)alloc((size_t)MP2 * 1024 * 2);   // hidden bf16; reused as attention output
    bf16* wqkv = (bf16*)alloc((size_t)3072 * 1024 * 2);
    bf16* wo   = (bf16*)alloc((size_t)1024 * 1024 * 2);
    bf16* qk   = (bf16*)alloc((size_t)MP2 * 2048 * 2);   // Q cols [0,1024), K cols [1024,2048)
    bf16* vT   = (bf16*)alloc((size_t)BH_ * 64 * SP * 2);

    int n4all = M_ * 256 + 4 * 262144 + BH_ * 64;
    cast_all<<<(n4all + 255) / 256, 256, 0, stream>>>(hs, qw, kw, vw, ow,
                                                      hsA, wqkv, wqkv + 1048576, wqkv + 2097152, wo, vT);

    gemm_qkv<<<73 * 12, 512, 0, stream>>>(hsA, wqkv, qb, kb, vb, qk, vT);
    attn_kernel<<<2560, 256, 0, stream>>>(qk, vT, hsA);
    gemm_out<<<145 * 4, 512, 0, stream>>>(hsA, wo, ob, (float*)d_out);
}

// Round 21
// 360.465 us; speedup vs baseline: 1.0270x; 1.0270x over previous
//
#include <hip/hip_runtime.h>
#include <hip/hip_bf16.h>
#include <stdint.h>

#define B_   32
#define S_   577
#define SP   640
#define D_   1024
#define H_   16
#define DH   64
#define BH_  (B_*H_)
#define M_   (B_*S_)      // 18464
#define MP2  18688        // padded to 256
#define SCALE_ 0.125f
#define LOG2E_ 1.44269504088896f

typedef __bf16 bf16;
typedef __bf16 bf16x8 __attribute__((ext_vector_type(8)));
typedef __bf16 bf16x4 __attribute__((ext_vector_type(4)));
typedef float  f32x4  __attribute__((ext_vector_type(4)));

__device__ __forceinline__ void gload16(const bf16* g, bf16* l) {
    __builtin_amdgcn_global_load_lds((__attribute__((address_space(1))) void*)g,
                                     (__attribute__((address_space(3))) void*)l, 16, 0, 0);
}

// ---------------- merged cast: hidden + 4 weights in one launch ----------------
__global__ void cast_all(const float* __restrict__ hs, const float* __restrict__ qw,
                         const float* __restrict__ kw, const float* __restrict__ vw,
                         const float* __restrict__ ow,
                         bf16* __restrict__ hsA, bf16* __restrict__ wq, bf16* __restrict__ wk,
                         bf16* __restrict__ wv, bf16* __restrict__ wo) {
    const int N4H = M_ * 256;                      // hidden float4 count
    int i = blockIdx.x * blockDim.x + threadIdx.x;
    if (i >= N4H + 4 * 262144) return;
    const float* in; bf16* out; int r;
    if (i < N4H) { in = hs; out = hsA; r = i; }
    else {
        int j = i - N4H, seg = j >> 18; r = j & 262143;
        in  = (seg == 0) ? qw : (seg == 1) ? kw : (seg == 2) ? vw : ow;
        out = (seg == 0) ? wq : (seg == 1) ? wk : (seg == 2) ? wv : wo;
    }
    float4 v = ((const float4*)in)[r];
    bf16x4 o;
    o[0] = (bf16)v.x; o[1] = (bf16)v.y; o[2] = (bf16)v.z; o[3] = (bf16)v.w;
    ((bf16x4*)out)[r] = o;
}

// zero only vT's padded s-columns [577,640) — replaces 42 MB memset with 4 MB
__global__ void zero_vpad(bf16* __restrict__ vT) {
    int i = blockIdx.x * blockDim.x + threadIdx.x;   // one thread per (bh*64) row
    if (i >= BH_ * 64) return;
    bf16* row = vT + (size_t)i * SP + S_;
    #pragma unroll
    for (int j = 0; j < SP - S_; ++j) row[j] = (bf16)0.0f;
}

// ---------------- 256x256 tile, BK=64, double-buffered 2-phase GEMM core (R8, best) ----------------
__device__ __forceinline__ void stage256(const bf16* __restrict__ A, const bf16* __restrict__ B,
                                         int m0, int n0, int K, int kt, bf16* SMbuf) {
    const int tid = threadIdx.x;
    const int wave = tid >> 6;
    #pragma unroll
    for (int ld = 0; ld < 8; ++ld) {
        int li  = ld * 512 + tid;
        int row = (li >> 3) & 255;
        int ch  = (li & 7) ^ (row & 7);
        const bf16* g = ((ld < 4) ? (A + (size_t)(m0 + row) * K)
                                  : (B + (size_t)(n0 + row) * K)) + kt * 64 + ch * 8;
        bf16* l = SMbuf + (size_t)(ld * 512 + wave * 64) * 8;
        gload16(g, l);
    }
}

__device__ __forceinline__ void compute256(const bf16* SMbuf, f32x4 acc[8][4],
                                           int wm, int wn, int r16, int c4) {
    #pragma unroll
    for (int kk = 0; kk < 2; ++kk) {
        bf16x8 bq[4];
        #pragma unroll
        for (int j = 0; j < 4; ++j) {
            int row = wn * 64 + j * 16 + r16;
            int c   = (kk * 4 + c4) ^ (row & 7);
            bq[j] = *(const bf16x8*)(SMbuf + 16384 + row * 64 + c * 8);
        }
        #pragma unroll
        for (int i = 0; i < 8; ++i) {
            int row = wm * 128 + i * 16 + r16;
            int c   = (kk * 4 + c4) ^ (row & 7);
            bf16x8 a = *(const bf16x8*)(SMbuf + row * 64 + c * 8);
            #pragma unroll
            for (int j = 0; j < 4; ++j)
                acc[i][j] = __builtin_amdgcn_mfma_f32_16x16x32_bf16(a, bq[j], acc[i][j], 0, 0, 0);
        }
    }
}

// ---------------- QKV projection: [MP2,1024] x [3072,1024]^T (R8 verbatim) ----------------
__global__ __launch_bounds__(512, 2) void gemm_qkv(const bf16* __restrict__ A, const bf16* __restrict__ Bw,
                                                   const float* __restrict__ qb, const float* __restrict__ kb,
                                                   const float* __restrict__ vb,
                                                   bf16* __restrict__ qk, bf16* __restrict__ vT) {
    __shared__ __align__(16) bf16 SM[2 * 32768];   // 128 KB
    const int bx = blockIdx.x;
    const int bm = bx / 12, bn = bx % 12;
    const int m0 = bm * 256, n0 = bn * 256;
    const int tid = threadIdx.x;
    const int lane = tid & 63, wave = tid >> 6;
    const int wm = wave >> 2, wn = wave & 3;
    const int r16 = lane & 15, c4 = lane >> 4;

    f32x4 acc[8][4];
    #pragma unroll
    for (int i = 0; i < 8; ++i)
        #pragma unroll
        for (int j = 0; j < 4; ++j)
            #pragma unroll
            for (int r = 0; r < 4; ++r) acc[i][j][r] = 0.0f;

    stage256(A, Bw, m0, n0, 1024, 0, SM);
    __syncthreads();
    for (int kt = 0; kt < 16; ++kt) {
        if (kt < 15) stage256(A, Bw, m0, n0, 1024, kt + 1, SM + ((kt + 1) & 1) * 32768);
        compute256(SM + (kt & 1) * 32768, acc, wm, wn, r16, c4);
        __syncthreads();
    }

    if (bn < 8) {
        const float* barr = (bn < 4) ? qb : kb;
        const float mul = (bn < 4) ? SCALE_ * LOG2E_ : 1.0f;
        #pragma unroll
        for (int j = 0; j < 4; ++j) {
            int n = n0 + wn * 64 + j * 16 + r16;
            float bias = barr[n & 1023];
            #pragma unroll
            for (int i = 0; i < 8; ++i) {
                #pragma unroll
                for (int r = 0; r < 4; ++r) {
                    int m = m0 + wm * 128 + i * 16 + c4 * 4 + r;
                    if (m < M_) qk[(size_t)m * 2048 + n] = (bf16)((acc[i][j][r] + bias) * mul);
                }
            }
        }
    } else {
        const int bnp = bn - 8;
        bf16* Ts = SM;                              // [128][259]
        #pragma unroll
        for (int mh = 0; mh < 2; ++mh) {
            if (wm == mh) {
                #pragma unroll
                for (int j = 0; j < 4; ++j) {
                    int nl = wn * 64 + j * 16 + r16;
                    float bias = vb[bnp * 256 + nl];
                    #pragma unroll
                    for (int i = 0; i < 8; ++i) {
                        #pragma unroll
                        for (int r = 0; r < 4; ++r) {
                            int tr = i * 16 + c4 * 4 + r;
                            Ts[tr * 259 + nl] = (bf16)(acc[i][j][r] + bias);
                        }
                    }
                }
            }
            __syncthreads();
            {
                int ml = tid & 127, nh = tid >> 7;
                int gm = m0 + mh * 128 + ml;
                if (gm < M_) {
                    unsigned bb = (unsigned)gm / 577u, s = (unsigned)gm - bb * 577u;
                    bf16* dst = vT + ((size_t)((bb * 16 + bnp * 4 + nh) * 64)) * SP + s;
                    const bf16* src = Ts + ml * 259 + nh * 64;
                    #pragma unroll 8
                    for (int j = 0; j < 64; ++j) dst[(size_t)j * SP] = src[j];
                }
            }
            __syncthreads();
        }
    }
}

// ---------------- output projection: 128x256 tile (R14) ----------------
__device__ __forceinline__ void stage_out(const bf16* __restrict__ A, const bf16* __restrict__ B,
                                          int m0, int n0, int kt, bf16* SMbuf) {
    const int tid = threadIdx.x;
    const int wave = tid >> 6;
    #pragma unroll
    for (int ld = 0; ld < 2; ++ld) {
        int li  = ld * 512 + tid;
        int row = li >> 3;
        int ch  = (li & 7) ^ (row & 7);
        gload16(A + (size_t)(m0 + row) * 1024 + kt * 64 + ch * 8,
                SMbuf + (size_t)(ld * 512 + wave * 64) * 8);
    }
    #pragma unroll
    for (int ld = 0; ld < 4; ++ld) {
        int li  = ld * 512 + tid;
        int row = li >> 3;
        int ch  = (li & 7) ^ (row & 7);
        gload16(B + (size_t)(n0 + row) * 1024 + kt * 64 + ch * 8,
                SMbuf + 8192 + (size_t)(ld * 512 + wave * 64) * 8);
    }
}

__global__ __launch_bounds__(512, 2) void gemm_out(const bf16* __restrict__ A, const bf16* __restrict__ Bw,
                                                   const float* __restrict__ ob, float* __restrict__ out) {
    __shared__ __align__(16) bf16 SM[2 * 24576];   // 96 KB
    const int bx = blockIdx.x;
    const int bm = bx >> 2, bn = bx & 3;
    const int m0 = bm * 128, n0 = bn * 256;
    const int tid = threadIdx.x;
    const int lane = tid & 63, wave = tid >> 6;
    const int wm = wave >> 2, wn = wave & 3;       // wave tile: 64 x 64
    const int r16 = lane & 15, c4 = lane >> 4;

    f32x4 acc[4][4];
    #pragma unroll
    for (int i = 0; i < 4; ++i)
        #pragma unroll
        for (int j = 0; j < 4; ++j)
            #pragma unroll
            for (int r = 0; r < 4; ++r) acc[i][j][r] = 0.0f;

    stage_out(A, Bw, m0, n0, 0, SM);
    __syncthreads();
    for (int kt = 0; kt < 16; ++kt) {
        if (kt < 15) stage_out(A, Bw, m0, n0, kt + 1, SM + ((kt + 1) & 1) * 24576);
        const bf16* SMbuf = SM + (kt & 1) * 24576;
        #pragma unroll
        for (int kk = 0; kk < 2; ++kk) {
            bf16x8 bq[4];
            #pragma unroll
            for (int j = 0; j < 4; ++j) {
                int row = wn * 64 + j * 16 + r16;
                int c   = (kk * 4 + c4) ^ (row & 7);
                bq[j] = *(const bf16x8*)(SMbuf + 8192 + row * 64 + c * 8);
            }
            #pragma unroll
            for (int i = 0; i < 4; ++i) {
                int row = wm * 64 + i * 16 + r16;
                int c   = (kk * 4 + c4) ^ (row & 7);
                bf16x8 a = *(const bf16x8*)(SMbuf + row * 64 + c * 8);
                #pragma unroll
                for (int j = 0; j < 4; ++j)
                    acc[i][j] = __builtin_amdgcn_mfma_f32_16x16x32_bf16(a, bq[j], acc[i][j], 0, 0, 0);
            }
        }
        __syncthreads();
    }

    #pragma unroll
    for (int j = 0; j < 4; ++j) {
        int n = n0 + wn * 64 + j * 16 + r16;
        float bias = ob[n];
        #pragma unroll
        for (int i = 0; i < 4; ++i) {
            #pragma unroll
            for (int r = 0; r < 4; ++r) {
                int m = m0 + wm * 64 + i * 16 + c4 * 4 + r;
                if (m < M_) out[(size_t)m * 1024 + n] = acc[i][j][r] + bias;
            }
        }
    }
}

// ---------------- flash attention v8 (R14/R16/R18 best): QBLK=128, per-qf softmax->PV, 40 KB LDS ----------------
__global__ __launch_bounds__(256) void attn_kernel(const bf16* __restrict__ qk,
                                                   const bf16* __restrict__ vT, bf16* __restrict__ obuf) {
    __shared__ __align__(16) bf16 KV[2][2][4096];      // [buf][K|V][64x64] = 32 KB
    __shared__ __align__(16) char Pls[4 * 2048];       // 8 KB (one P tile per wave)
    const int orig = blockIdx.x;
    const int xcd = orig & 7;
    const int t   = orig >> 3;
    const int qt  = t % 5, bhg = t / 5;
    const int bh  = bhg * 8 + xcd;
    const int b   = bh >> 4, h = bh & 15;
    const int tid = threadIdx.x;
    const int lane = tid & 63, wave = tid >> 6;
    const int r16 = lane & 15, c4 = lane >> 4;
    const int q0  = qt * 128 + wave * 32;
    const int swz = (r16 & 7) << 4;

    const bf16* qp = qk + (size_t)(b * 577) * 2048 + h * 64;
    const bf16* kp = qp + 1024;
    const bf16* vp = vT + (size_t)bh * 64 * SP;

    bf16x8 aq[2][2];
    #pragma unroll
    for (int qf = 0; qf < 2; ++qf)
        #pragma unroll
        for (int c = 0; c < 2; ++c)
            aq[qf][c] = *(const bf16x8*)(qp + (size_t)(q0 + qf * 16 + r16) * 2048 + c * 32 + c4 * 8);

    float mi[2] = {-3.0e38f, -3.0e38f};
    float li[2] = {0.0f, 0.0f};
    f32x4 accO[2][4];
    #pragma unroll
    for (int qf = 0; qf < 2; ++qf)
        #pragma unroll
        for (int nt = 0; nt < 4; ++nt)
            #pragma unroll
            for (int r = 0; r < 4; ++r) accO[qf][nt][r] = 0.0f;

    char* pbase = Pls + wave * 2048 + r16 * 128;

    auto stageKV = [&](int kt, int buf) {
        #pragma unroll
        for (int half = 0; half < 2; ++half) {
            int li  = half * 256 + tid;
            int row = li >> 3;
            int ch  = (li & 7) ^ (row & 7);            // inverse-swizzled source
            bf16* lk = &KV[buf][0][(size_t)(half * 256 + wave * 64) * 8];
            bf16* lv = &KV[buf][1][(size_t)(half * 256 + wave * 64) * 8];
            gload16(kp + (size_t)(kt * 64 + row) * 2048 + ch * 8, lk);
            gload16(vp + (size_t)row * SP + kt * 64 + ch * 8, lv);
        }
    };

    stageKV(0, 0);
    __syncthreads();

    for (int kt = 0; kt < 10; ++kt) {
        const int buf = kt & 1;
        if (kt < 9) stageKV(kt + 1, buf ^ 1);          // async, drained by loop-end barrier

        // ---- K fragments from LDS (swizzled read) + QK^T, both qf ----
        bf16x8 kf[4][2];
        #pragma unroll
        for (int nt = 0; nt < 4; ++nt)
            #pragma unroll
            for (int c = 0; c < 2; ++c) {
                int row = nt * 16 + r16;
                int cc  = (c * 4 + c4) ^ (row & 7);
                kf[nt][c] = *(const bf16x8*)(&KV[buf][0][row * 64 + cc * 8]);
            }
        f32x4 sc[2][4];
        #pragma unroll
        for (int qf = 0; qf < 2; ++qf)
            #pragma unroll
            for (int nt = 0; nt < 4; ++nt) {
                f32x4 z = {0.0f, 0.0f, 0.0f, 0.0f};
                z = __builtin_amdgcn_mfma_f32_16x16x32_bf16(kf[nt][0], aq[qf][0], z, 0, 0, 0);
                sc[qf][nt] = __builtin_amdgcn_mfma_f32_16x16x32_bf16(kf[nt][1], aq[qf][1], z, 0, 0, 0);
            }

        // ---- V fragments once per tile (shared by both qf) ----
        bf16x8 vf[4][2];
        #pragma unroll
        for (int ntd = 0; ntd < 4; ++ntd)
            #pragma unroll
            for (int kk = 0; kk < 2; ++kk) {
                int row = ntd * 16 + r16;
                int cc  = (kk * 4 + c4) ^ (row & 7);
                vf[ntd][kk] = *(const bf16x8*)(&KV[buf][1][row * 64 + cc * 8]);
            }

        // ---- per qf: softmax -> P-LDS -> PV (single P buffer reused) ----
        #pragma unroll
        for (int qf = 0; qf < 2; ++qf) {
            if (kt == 9) {   // only k=576 valid in last tile
                #pragma unroll
                for (int nt = 0; nt < 4; ++nt)
                    #pragma unroll
                    for (int r = 0; r < 4; ++r)
                        if (576 + nt * 16 + c4 * 4 + r >= S_) sc[qf][nt][r] = -3.0e38f;
            }
            float pmax = sc[qf][0][0];
            #pragma unroll
            for (int nt = 0; nt < 4; ++nt)
                #pragma unroll
                for (int r = 0; r < 4; ++r) pmax = fmaxf(pmax, sc[qf][nt][r]);
            pmax = fmaxf(pmax, __shfl_xor(pmax, 16));
            pmax = fmaxf(pmax, __shfl_xor(pmax, 32));

            const bool vrow = (q0 + qf * 16 + r16) < S_;
            int ok = (!vrow) || (pmax <= mi[qf] + 8.0f);
            if (!__all(ok)) {
                float mnew = fmaxf(mi[qf], pmax);
                float fsc  = __builtin_amdgcn_exp2f(mi[qf] - mnew);
                mi[qf] = mnew;
                li[qf] *= fsc;
                float fs0 = __shfl(fsc, c4 * 4 + 0);
                float fs1 = __shfl(fsc, c4 * 4 + 1);
                float fs2 = __shfl(fsc, c4 * 4 + 2);
                float fs3 = __shfl(fsc, c4 * 4 + 3);
                #pragma unroll
                for (int nt = 0; nt < 4; ++nt) {
                    accO[qf][nt][0] *= fs0; accO[qf][nt][1] *= fs1;
                    accO[qf][nt][2] *= fs2; accO[qf][nt][3] *= fs3;
                }
            }
            float p[4][4];
            float rs = 0.0f;
            #pragma unroll
            for (int nt = 0; nt < 4; ++nt)
                #pragma unroll
                for (int r = 0; r < 4; ++r) {
                    p[nt][r] = __builtin_amdgcn_exp2f(sc[qf][nt][r] - mi[qf]);
                    rs += p[nt][r];
                }
            rs += __shfl_xor(rs, 16);
            rs += __shfl_xor(rs, 32);
            li[qf] += rs;
            #pragma unroll
            for (int nt = 0; nt < 4; ++nt) {
                bf16x4 pk;
                pk[0] = (bf16)p[nt][0]; pk[1] = (bf16)p[nt][1];
                pk[2] = (bf16)p[nt][2]; pk[3] = (bf16)p[nt][3];
                *(bf16x4*)(pbase + ((nt * 32 + c4 * 8) ^ swz)) = pk;
            }

            bf16x8 pf[2];
            #pragma unroll
            for (int kk = 0; kk < 2; ++kk)
                pf[kk] = *(const bf16x8*)(pbase + ((kk * 64 + c4 * 16) ^ swz));
            #pragma unroll
            for (int ntd = 0; ntd < 4; ++ntd)
                #pragma unroll
                for (int kk = 0; kk < 2; ++kk)
                    accO[qf][ntd] = __builtin_amdgcn_mfma_f32_16x16x32_bf16(pf[kk], vf[ntd][kk], accO[qf][ntd], 0, 0, 0);
        }

        __syncthreads();   // drains stage(kt+1) + guards buf reuse
    }

    // ---- epilogue ----
    #pragma unroll
    for (int qf = 0; qf < 2; ++qf) {
        float inv = 1.0f / li[qf];
        float rl0 = __shfl(inv, c4 * 4 + 0);
        float rl1 = __shfl(inv, c4 * 4 + 1);
        float rl2 = __shfl(inv, c4 * 4 + 2);
        float rl3 = __shfl(inv, c4 * 4 + 3);
        #pragma unroll
        for (int ntd = 0; ntd < 4; ++ntd) {
            #pragma unroll
            for (int r = 0; r < 4; ++r) {
                int s = q0 + qf * 16 + c4 * 4 + r;
                if (s < S_) {
                    float rl = (r == 0) ? rl0 : (r == 1) ? rl1 : (r == 2) ? rl2 : rl3;
                    obuf[((size_t)(b * S_ + s)) * 1024 + h * 64 + ntd * 16 + r16] =
                        (bf16)(accO[qf][ntd][r] * rl);
                }
            }
        }
    }
}

extern "C" void kernel_launch(void* const* d_in, const int* in_sizes, int n_in,
                              void* d_out, int out_size, void* d_ws, size_t ws_size,
                              hipStream_t stream) {
    const float* hs = (const float*)d_in[0];
    const float* qw = (const float*)d_in[1];
    const float* qb = (const float*)d_in[2];
    const float* kw = (const float*)d_in[3];
    const float* kb = (const float*)d_in[4];
    const float* vw = (const float*)d_in[5];
    const float* vb = (const float*)d_in[6];
    const float* ow = (const float*)d_in[7];
    const float* ob = (const float*)d_in[8];

    char* ws = (char*)d_ws;
    size_t off = 0;
    auto alloc = [&](size_t bytes) { void* p = ws + off; off += (bytes + 255) & ~255UL; return p; };
    bf16* hsA  = (bf16*)alloc((size_t)MP2 * 1024 * 2);   // hidden bf16; reused as attention output
    bf16* wqkv = (bf16*)alloc((size_t)3072 * 1024 * 2);
    bf16* wo   = (bf16*)alloc((size_t)1024 * 1024 * 2);
    bf16* qk   = (bf16*)alloc((size_t)MP2 * 2048 * 2);   // Q cols [0,1024), K cols [1024,2048)
    bf16* vT   = (bf16*)alloc((size_t)BH_ * 64 * SP * 2);

    zero_vpad<<<(BH_ * 64 + 255) / 256, 256, 0, stream>>>(vT);

    int n4all = M_ * 256 + 4 * 262144;
    cast_all<<<(n4all + 255) / 256, 256, 0, stream>>>(hs, qw, kw, vw, ow,
                                                      hsA, wqkv, wqkv + 1048576, wqkv + 2097152, wo);

    gemm_qkv<<<73 * 12, 512, 0, stream>>>(hsA, wqkv, qb, kb, vb, qk, vT);
    attn_kernel<<<2560, 256, 0, stream>>>(qk, vT, hsA);
    gemm_out<<<145 * 4, 512, 0, stream>>>(hsA, wo, ob, (float*)d_out);
}